// Round 5
// baseline (117.243 us; speedup 1.0000x reference)
//
#include <hip/hip_runtime.h>

// Problem dims (fixed by reference)
#define BB 2
#define CC 2
#define DD 96
#define HH 192
#define WW 192
static constexpr int NV   = BB * DD * HH * WW;   // 7,077,888 voxels
static constexpr int HW_  = HH * WW;             // 36,864
static constexpr int DHW_ = DD * HW_;            // 3,538,944
static constexpr int ROWS = BB * DD * HH;        // 36,864 W-rows
static constexpr int QPR  = WW / 4;              // 48 int4-quads per row

// k_wh geometry: block = (b,d) slice x 8-quad W-segment, full H in LDS
static constexpr int SEGQ = 8;                   // quads per segment (32 voxels)
static constexpr int NSEG = QPR / SEGQ;          // 6
static constexpr int LSTR = SEGQ + 1;            // LDS row stride (uint2), padded
static constexpr int WHBLKS = BB * DD * NSEG;    // 1152

// k_loss geometry: 192 threads, 8 voxels/thread, 16 rows/block
static constexpr int LBLKS = ROWS / 16;          // 2304

// fixed-point window-combination constants: 27*125*343 = 1,157,625
// fq = (cnum - 2*(S3*42875 + S5*9261 + S7*3375)) / 1157625
#define K3 42875
#define K5 9261
#define K7 3375

// packed-field masks (2 ushorts per uint32)
#define PM1  0x00010001u
#define PM3  0x00030003u
#define PM7  0x00070007u
#define PMF  0x000F000Fu
#define PM1F 0x001F001Fu
#define PM3F 0x003F003Fu

// ---------------------------------------------------------------------------
// k_wh: fused W-window + H-window sums (unchanged from R4 — verified).
// ---------------------------------------------------------------------------
__device__ __forceinline__ unsigned ypack(const unsigned* g) {
    unsigned t3 = ((g[2] >> 1) & PM3) + ((g[3] >> 1) & PM3) + ((g[4] >> 1) & PM3);
    unsigned t5 = ((g[1] >> 3) & PM7) + ((g[2] >> 3) & PM7) + ((g[3] >> 3) & PM7)
                + ((g[4] >> 3) & PM7) + ((g[5] >> 3) & PM7);
    unsigned t7 = ((g[0] >> 6) & PM7) + ((g[1] >> 6) & PM7) + ((g[2] >> 6) & PM7)
                + ((g[3] >> 6) & PM7) + ((g[4] >> 6) & PM7) + ((g[5] >> 6) & PM7)
                + ((g[6] >> 6) & PM7);
    return (g[3] & PM1) | (t3 << 1) | (t5 << 5) | (t7 << 10);
}

__global__ __launch_bounds__(256) void k_wh(const int* __restrict__ lab,
                                            unsigned short* __restrict__ ys) {
    __shared__ uint2 lds[HH * LSTR];             // 13,824 B
    int blk  = blockIdx.x;
    int seg  = blk % NSEG;
    int bd   = blk / NSEG;                       // (b*DD + d), 0..191
    int base = bd * HW_;                         // voxel index of (b,d,0,0)
    const int4* l4 = (const int4*)lab;
    int bq = base >> 2;

    // ---- Stage A: W-sums -> LDS -----------------------------------------
    for (int t = threadIdx.x; t < HH * SEGQ; t += 256) {
        int row  = t >> 3;
        int qloc = t & 7;
        int gq   = seg * SEGQ + qloc;
        int qi   = bq + row * QPR + gq;
        int4 cur = l4[qi];
        int4 prv = (gq > 0)       ? l4[qi - 1] : int4{0, 0, 0, 0};
        int4 nxt = (gq < QPR - 1) ? l4[qi + 1] : int4{0, 0, 0, 0};
        int v[12] = {prv.x, prv.y, prv.z, prv.w,
                     cur.x, cur.y, cur.z, cur.w,
                     nxt.x, nxt.y, nxt.z, nxt.w};
        int s7[4], s5[4], s3[4];
        s7[0] = v[1] + v[2] + v[3] + v[4] + v[5] + v[6] + v[7];
#pragma unroll
        for (int j = 0; j < 3; ++j) s7[j + 1] = s7[j] - v[j + 1] + v[j + 8];
#pragma unroll
        for (int j = 0; j < 4; ++j) {
            s5[j] = s7[j] - v[j + 1] - v[j + 7];
            s3[j] = s5[j] - v[j + 2] - v[j + 6];
        }
        unsigned o0 = (unsigned)(v[4] | (s3[0] << 1) | (s5[0] << 3) | (s7[0] << 6));
        unsigned o1 = (unsigned)(v[5] | (s3[1] << 1) | (s5[1] << 3) | (s7[1] << 6));
        unsigned o2 = (unsigned)(v[6] | (s3[2] << 1) | (s5[2] << 3) | (s7[2] << 6));
        unsigned o3 = (unsigned)(v[7] | (s3[3] << 1) | (s5[3] << 3) | (s7[3] << 6));
        uint2 st;
        st.x = o0 | (o1 << 16);
        st.y = o2 | (o3 << 16);
        lds[row * LSTR + qloc] = st;
    }
    __syncthreads();

    // ---- Stage B: H-sums -> ys ------------------------------------------
    for (int t = threadIdx.x; t < HH * SEGQ; t += 256) {
        int row  = t >> 3;
        int qloc = t & 7;
        int gq   = seg * SEGQ + qloc;
        unsigned gx[7], gy[7];
#pragma unroll
        for (int k = 0; k < 7; ++k) {
            int hh = row + k - 3;
            if (hh >= 0 && hh < HH) {
                uint2 u = lds[hh * LSTR + qloc];
                gx[k] = u.x; gy[k] = u.y;
            } else { gx[k] = 0u; gy[k] = 0u; }
        }
        uint2 st;
        st.x = ypack(gx);
        st.y = ypack(gy);
        *(uint2*)(ys + base + row * WW + gq * 4) = st;
    }
}

// ---------------------------------------------------------------------------
// k_loss: D-window SWAR sums; exact fixed-point fq; wm = 3 + sgn*fq;
// nll = softplus(sgn*(l0-l1)); block partials; LAST block finalizes the
// scalar loss (atomic-counter done pattern; counter memset to 0 each call).
// ---------------------------------------------------------------------------
__global__ __launch_bounds__(192) void k_loss(const unsigned short* __restrict__ ys,
                                              const float* __restrict__ logits,
                                              float* __restrict__ p_nll,
                                              float* __restrict__ p_nw,
                                              float* __restrict__ p_wm,
                                              unsigned* __restrict__ counter,
                                              float* __restrict__ out) {
    int tid  = threadIdx.x;
    int rloc = tid / 24;          // 0..7
    int q8   = tid % 24;          // 8-voxel group within row
    bool interior = (q8 > 0) && (q8 < 23);

    float acc_n = 0.f, acc_p = 0.f, mx = 0.f;

#pragma unroll
    for (int it = 0; it < 2; ++it) {
        int row = blockIdx.x * 16 + it * 8 + rloc;
        int h   = row % HH;
        int rd  = row / HH;
        int d   = rd % DD;
        int b   = rd / DD;
        int i0  = row * WW + q8 * 8;

        unsigned u[7][4];
#pragma unroll
        for (int k = 0; k < 7; ++k) {
            int dd = d + k - 3;
            if (dd >= 0 && dd < DD) {
                uint4 t4 = *(const uint4*)(ys + i0 + (k - 3) * HW_);
                u[k][0] = t4.x; u[k][1] = t4.y; u[k][2] = t4.z; u[k][3] = t4.w;
            } else {
                u[k][0] = 0u; u[k][1] = 0u; u[k][2] = 0u; u[k][3] = 0u;
            }
        }
        unsigned S3[4], S5[4], S7[4];
#pragma unroll
        for (int w = 0; w < 4; ++w) {
            S3[w] = ((u[2][w] >> 1) & PMF) + ((u[3][w] >> 1) & PMF) + ((u[4][w] >> 1) & PMF);
            S5[w] = ((u[1][w] >> 5) & PM1F) + ((u[2][w] >> 5) & PM1F) + ((u[3][w] >> 5) & PM1F)
                  + ((u[4][w] >> 5) & PM1F) + ((u[5][w] >> 5) & PM1F);
            S7[w] = ((u[0][w] >> 10) & PM3F) + ((u[1][w] >> 10) & PM3F) + ((u[2][w] >> 10) & PM3F)
                  + ((u[3][w] >> 10) & PM3F) + ((u[4][w] >> 10) & PM3F) + ((u[5][w] >> 10) & PM3F)
                  + ((u[6][w] >> 10) & PM3F);
        }

        int ch3 = 1 + min(h, 1) + min(HH - 1 - h, 1);
        int ch5 = 1 + min(h, 2) + min(HH - 1 - h, 2);
        int ch7 = 1 + min(h, 3) + min(HH - 1 - h, 3);
        int cd3 = 1 + min(d, 1) + min(DD - 1 - d, 1);
        int cd5 = 1 + min(d, 2) + min(DD - 1 - d, 2);
        int cd7 = 1 + min(d, 3) + min(DD - 1 - d, 3);
        int A3 = ch3 * cd3 * K3;             // <= 9*42875  = 385,875 < 2^24
        int B5 = ch5 * cd5 * K5;             // <= 25*9261  = 231,525 < 2^24
        int C7 = ch7 * cd7 * K7;             // <= 49*3375  = 165,375 < 2^24
        int inum = 3 * A3 + 5 * B5 + 7 * C7; // interior cnum

        const float* lp = logits + i0 + b * DHW_;
        const float4 A0 = *(const float4*)(lp);
        const float4 A1 = *(const float4*)(lp + 4);
        const float4 B0 = *(const float4*)(lp + DHW_);
        const float4 B1 = *(const float4*)(lp + DHW_ + 4);
        float l0[8] = {A0.x, A0.y, A0.z, A0.w, A1.x, A1.y, A1.z, A1.w};
        float l1[8] = {B0.x, B0.y, B0.z, B0.w, B1.x, B1.y, B1.z, B1.w};

#pragma unroll
        for (int j = 0; j < 8; ++j) {
            const int wd = j >> 1;
            const int sh = (j & 1) * 16;
            int S3j  = (int)((S3[wd] >> sh) & 0xFFFFu);
            int S5j  = (int)((S5[wd] >> sh) & 0xFFFFu);
            int S7j  = (int)((S7[wd] >> sh) & 0xFFFFu);
            int labj = (int)((u[3][wd] >> sh) & 1u);

            int Ssum = __mul24(S3j, K3) + __mul24(S5j, K5) + __mul24(S7j, K7);
            int cn = inum;
            if (!interior) {
                int w = q8 * 8 + j;
                int cw3 = 1 + min(w, 1) + min(WW - 1 - w, 1);
                int cw5 = 1 + min(w, 2) + min(WW - 1 - w, 2);
                int cw7 = 1 + min(w, 3) + min(WW - 1 - w, 3);
                cn = __mul24(cw3, A3) + __mul24(cw5, B5) + __mul24(cw7, C7);
            }
            float fq  = (float)(cn - 2 * Ssum) * (1.0f / 1157625.0f);
            float sgn = labj ? 1.0f : -1.0f;
            float wm  = fmaf(sgn, fq, 3.0f);
            float s   = sgn * (l0[j] - l1[j]);
            float nll = fmaxf(s, 0.f) + __logf(1.0f + __expf(-fabsf(s)));

            acc_n += nll;
            acc_p += nll * wm;
            mx = fmaxf(mx, wm);
        }
    }

    // reduce 3 waves
#pragma unroll
    for (int off = 32; off > 0; off >>= 1) {
        acc_n += __shfl_down(acc_n, off);
        acc_p += __shfl_down(acc_p, off);
        mx     = fmaxf(mx, __shfl_down(mx, off));
    }
    __shared__ float s_n[3], s_p[3], s_m[3];
    __shared__ int   is_last;
    int wid  = tid >> 6;
    int lane = tid & 63;
    if (lane == 0) { s_n[wid] = acc_n; s_p[wid] = acc_p; s_m[wid] = mx; }
    __syncthreads();
    if (tid == 0) {
        p_nll[blockIdx.x] = s_n[0] + s_n[1] + s_n[2];
        p_nw[blockIdx.x]  = s_p[0] + s_p[1] + s_p[2];
        p_wm[blockIdx.x]  = fmaxf(s_m[0], fmaxf(s_m[1], s_m[2]));
        __threadfence();                                  // publish partials
        is_last = (atomicAdd(counter, 1u) == LBLKS - 1);
    }
    __syncthreads();
    if (!is_last) return;

    // ---- final reduction by the last block -------------------------------
    __threadfence();                                      // acquire partials
    double s = 0.0, p = 0.0;
    float m2 = 0.f;
    for (int t = tid; t < LBLKS; t += 192) {
        s += (double)p_nll[t];
        p += (double)p_nw[t];
        m2 = fmaxf(m2, p_wm[t]);
    }
#pragma unroll
    for (int off = 32; off > 0; off >>= 1) {
        s  += __shfl_down(s, off);
        p  += __shfl_down(p, off);
        m2  = fmaxf(m2, __shfl_down(m2, off));
    }
    __shared__ double f_s[3], f_p[3];
    __shared__ float  f_m[3];
    if (lane == 0) { f_s[wid] = s; f_p[wid] = p; f_m[wid] = m2; }
    __syncthreads();
    if (tid == 0) {
        double S = f_s[0] + f_s[1] + f_s[2];
        double P = f_p[0] + f_p[1] + f_p[2];
        float  M = fmaxf(f_m[0], fmaxf(f_m[1], f_m[2]));
        double res = (M > 0.f) ? (S + 2.0 * P / (double)M) : S;
        out[0] = (float)(res / (double)NV);
    }
}

extern "C" void kernel_launch(void* const* d_in, const int* in_sizes, int n_in,
                              void* d_out, int out_size, void* d_ws, size_t ws_size,
                              hipStream_t stream) {
    const float* logits = (const float*)d_in[0];
    const int*   labels = (const int*)d_in[1];
    float*       out    = (float*)d_out;

    char* ws = (char*)d_ws;
    float*    p_nll   = (float*)ws;                     // LBLKS floats
    float*    p_nw    = (float*)(ws + 16384);           // LBLKS floats
    float*    p_wm    = (float*)(ws + 32768);           // LBLKS floats
    unsigned* counter = (unsigned*)(ws + 49152);        // 4 B done-counter
    unsigned short* ys = (unsigned short*)(ws + 65536);
    // ws use: 64 KB + NV*2 B ~= 14.2 MB; partials fully rewritten each call,
    // counter memset each call -> deterministic across graph replays.

    hipMemsetAsync(counter, 0, 4, stream);
    k_wh  <<<WHBLKS, 256, 0, stream>>>(labels, ys);
    k_loss<<<LBLKS, 192, 0, stream>>>(ys, logits, p_nll, p_nw, p_wm, counter, out);
}

// Round 6
// 45.486 us; speedup vs baseline: 2.5775x; 2.5775x over previous
//
#include <hip/hip_runtime.h>

// Problem dims (fixed by reference)
#define BB 2
#define CC 2
#define DD 96
#define HH 192
#define WW 192
static constexpr int NV   = BB * DD * HH * WW;   // 7,077,888 voxels
static constexpr int HW_  = HH * WW;             // 36,864
static constexpr int DHW_ = DD * HW_;            // 3,538,944
static constexpr int ROWS = BB * DD * HH;        // 36,864 W-rows
static constexpr int QPR  = WW / 4;              // 48 int4-quads per row

// k_wh geometry: block = (b,d) slice x 8-quad W-segment, full H in LDS
static constexpr int SEGQ = 8;                   // quads per segment (32 voxels)
static constexpr int NSEG = QPR / SEGQ;          // 6
static constexpr int LSTR = SEGQ + 1;            // LDS row stride (uint2), padded
static constexpr int WHBLKS = BB * DD * NSEG;    // 1152

// k_loss geometry: 192 threads, 8 voxels/thread, 16 rows/block
static constexpr int LBLKS = ROWS / 16;          // 2304

// fixed-point window-combination constants: 27*125*343 = 1,157,625
// fq = (cnum - 2*(S3*42875 + S5*9261 + S7*3375)) / 1157625   (exact in int)
#define K3 42875
#define K5 9261
#define K7 3375

// packed-field masks (2 ushorts per uint32)
#define PM1  0x00010001u
#define PM3  0x00030003u
#define PM7  0x00070007u
#define PMF  0x000F000Fu
#define PM1F 0x001F001Fu
#define PM3F 0x003F003Fu

// ---------------------------------------------------------------------------
// k_wh: fused W-window + H-window sums (R4-verified).
// ---------------------------------------------------------------------------
__device__ __forceinline__ unsigned ypack(const unsigned* g) {
    unsigned t3 = ((g[2] >> 1) & PM3) + ((g[3] >> 1) & PM3) + ((g[4] >> 1) & PM3);
    unsigned t5 = ((g[1] >> 3) & PM7) + ((g[2] >> 3) & PM7) + ((g[3] >> 3) & PM7)
                + ((g[4] >> 3) & PM7) + ((g[5] >> 3) & PM7);
    unsigned t7 = ((g[0] >> 6) & PM7) + ((g[1] >> 6) & PM7) + ((g[2] >> 6) & PM7)
                + ((g[3] >> 6) & PM7) + ((g[4] >> 6) & PM7) + ((g[5] >> 6) & PM7)
                + ((g[6] >> 6) & PM7);
    return (g[3] & PM1) | (t3 << 1) | (t5 << 5) | (t7 << 10);
}

__global__ __launch_bounds__(256) void k_wh(const int* __restrict__ lab,
                                            unsigned short* __restrict__ ys) {
    __shared__ uint2 lds[HH * LSTR];             // 13,824 B
    int blk  = blockIdx.x;
    int seg  = blk % NSEG;
    int bd   = blk / NSEG;                       // (b*DD + d), 0..191
    int base = bd * HW_;                         // voxel index of (b,d,0,0)
    const int4* l4 = (const int4*)lab;
    int bq = base >> 2;

    // ---- Stage A: W-sums -> LDS -----------------------------------------
    for (int t = threadIdx.x; t < HH * SEGQ; t += 256) {
        int row  = t >> 3;
        int qloc = t & 7;
        int gq   = seg * SEGQ + qloc;
        int qi   = bq + row * QPR + gq;
        int4 cur = l4[qi];
        int4 prv = (gq > 0)       ? l4[qi - 1] : int4{0, 0, 0, 0};
        int4 nxt = (gq < QPR - 1) ? l4[qi + 1] : int4{0, 0, 0, 0};
        int v[12] = {prv.x, prv.y, prv.z, prv.w,
                     cur.x, cur.y, cur.z, cur.w,
                     nxt.x, nxt.y, nxt.z, nxt.w};
        int s7[4], s5[4], s3[4];
        s7[0] = v[1] + v[2] + v[3] + v[4] + v[5] + v[6] + v[7];
#pragma unroll
        for (int j = 0; j < 3; ++j) s7[j + 1] = s7[j] - v[j + 1] + v[j + 8];
#pragma unroll
        for (int j = 0; j < 4; ++j) {
            s5[j] = s7[j] - v[j + 1] - v[j + 7];
            s3[j] = s5[j] - v[j + 2] - v[j + 6];
        }
        unsigned o0 = (unsigned)(v[4] | (s3[0] << 1) | (s5[0] << 3) | (s7[0] << 6));
        unsigned o1 = (unsigned)(v[5] | (s3[1] << 1) | (s5[1] << 3) | (s7[1] << 6));
        unsigned o2 = (unsigned)(v[6] | (s3[2] << 1) | (s5[2] << 3) | (s7[2] << 6));
        unsigned o3 = (unsigned)(v[7] | (s3[3] << 1) | (s5[3] << 3) | (s7[3] << 6));
        uint2 st;
        st.x = o0 | (o1 << 16);
        st.y = o2 | (o3 << 16);
        lds[row * LSTR + qloc] = st;
    }
    __syncthreads();

    // ---- Stage B: H-sums -> ys ------------------------------------------
    for (int t = threadIdx.x; t < HH * SEGQ; t += 256) {
        int row  = t >> 3;
        int qloc = t & 7;
        int gq   = seg * SEGQ + qloc;
        unsigned gx[7], gy[7];
#pragma unroll
        for (int k = 0; k < 7; ++k) {
            int hh = row + k - 3;
            if (hh >= 0 && hh < HH) {
                uint2 u = lds[hh * LSTR + qloc];
                gx[k] = u.x; gy[k] = u.y;
            } else { gx[k] = 0u; gy[k] = 0u; }
        }
        uint2 st;
        st.x = ypack(gx);
        st.y = ypack(gy);
        *(uint2*)(ys + base + row * WW + gq * 4) = st;
    }
}

// ---------------------------------------------------------------------------
// k_loss: D-window SWAR sums; exact fixed-point fq; wm = 3 + sgn*fq;
// nll = softplus(sgn*(l0-l1)); per-block partials (NO atomics/fences —
// R5 showed device-scope fence per block costs ~75 us chip-wide).
// ---------------------------------------------------------------------------
__global__ __launch_bounds__(192) void k_loss(const unsigned short* __restrict__ ys,
                                              const float* __restrict__ logits,
                                              float* __restrict__ p_nll,
                                              float* __restrict__ p_nw,
                                              float* __restrict__ p_wm) {
    int tid  = threadIdx.x;
    int rloc = tid / 24;          // 0..7
    int q8   = tid % 24;          // 8-voxel group within row
    bool interior = (q8 > 0) && (q8 < 23);

    float acc_n = 0.f, acc_p = 0.f, mx = 0.f;

#pragma unroll
    for (int it = 0; it < 2; ++it) {
        int row = blockIdx.x * 16 + it * 8 + rloc;
        int h   = row % HH;
        int rd  = row / HH;
        int d   = rd % DD;
        int b   = rd / DD;
        int i0  = row * WW + q8 * 8;

        unsigned u[7][4];
#pragma unroll
        for (int k = 0; k < 7; ++k) {
            int dd = d + k - 3;
            if (dd >= 0 && dd < DD) {
                uint4 t4 = *(const uint4*)(ys + i0 + (k - 3) * HW_);
                u[k][0] = t4.x; u[k][1] = t4.y; u[k][2] = t4.z; u[k][3] = t4.w;
            } else {
                u[k][0] = 0u; u[k][1] = 0u; u[k][2] = 0u; u[k][3] = 0u;
            }
        }
        unsigned S3[4], S5[4], S7[4];
#pragma unroll
        for (int w = 0; w < 4; ++w) {
            S3[w] = ((u[2][w] >> 1) & PMF) + ((u[3][w] >> 1) & PMF) + ((u[4][w] >> 1) & PMF);
            S5[w] = ((u[1][w] >> 5) & PM1F) + ((u[2][w] >> 5) & PM1F) + ((u[3][w] >> 5) & PM1F)
                  + ((u[4][w] >> 5) & PM1F) + ((u[5][w] >> 5) & PM1F);
            S7[w] = ((u[0][w] >> 10) & PM3F) + ((u[1][w] >> 10) & PM3F) + ((u[2][w] >> 10) & PM3F)
                  + ((u[3][w] >> 10) & PM3F) + ((u[4][w] >> 10) & PM3F) + ((u[5][w] >> 10) & PM3F)
                  + ((u[6][w] >> 10) & PM3F);
        }

        int ch3 = 1 + min(h, 1) + min(HH - 1 - h, 1);
        int ch5 = 1 + min(h, 2) + min(HH - 1 - h, 2);
        int ch7 = 1 + min(h, 3) + min(HH - 1 - h, 3);
        int cd3 = 1 + min(d, 1) + min(DD - 1 - d, 1);
        int cd5 = 1 + min(d, 2) + min(DD - 1 - d, 2);
        int cd7 = 1 + min(d, 3) + min(DD - 1 - d, 3);
        int A3 = ch3 * cd3 * K3;             // <= 385,875 < 2^24
        int B5 = ch5 * cd5 * K5;             // <= 231,525 < 2^24
        int C7 = ch7 * cd7 * K7;             // <= 165,375 < 2^24
        int inum = 3 * A3 + 5 * B5 + 7 * C7; // interior cnum

        const float* lp = logits + i0 + b * DHW_;
        const float4 A0 = *(const float4*)(lp);
        const float4 A1 = *(const float4*)(lp + 4);
        const float4 B0 = *(const float4*)(lp + DHW_);
        const float4 B1 = *(const float4*)(lp + DHW_ + 4);
        float l0[8] = {A0.x, A0.y, A0.z, A0.w, A1.x, A1.y, A1.z, A1.w};
        float l1[8] = {B0.x, B0.y, B0.z, B0.w, B1.x, B1.y, B1.z, B1.w};

#pragma unroll
        for (int j = 0; j < 8; ++j) {
            const int wd = j >> 1;
            const int sh = (j & 1) * 16;
            int S3j  = (int)((S3[wd] >> sh) & 0xFFFFu);
            int S5j  = (int)((S5[wd] >> sh) & 0xFFFFu);
            int S7j  = (int)((S7[wd] >> sh) & 0xFFFFu);
            int labj = (int)((u[3][wd] >> sh) & 1u);

            int Ssum = __mul24(S3j, K3) + __mul24(S5j, K5) + __mul24(S7j, K7);
            int cn = inum;
            if (!interior) {
                int w = q8 * 8 + j;
                int cw3 = 1 + min(w, 1) + min(WW - 1 - w, 1);
                int cw5 = 1 + min(w, 2) + min(WW - 1 - w, 2);
                int cw7 = 1 + min(w, 3) + min(WW - 1 - w, 3);
                cn = __mul24(cw3, A3) + __mul24(cw5, B5) + __mul24(cw7, C7);
            }
            float fq  = (float)(cn - 2 * Ssum) * (1.0f / 1157625.0f);
            float sgn = labj ? 1.0f : -1.0f;
            float wm  = fmaf(sgn, fq, 3.0f);
            float s   = sgn * (l0[j] - l1[j]);
            float nll = fmaxf(s, 0.f) + __logf(1.0f + __expf(-fabsf(s)));

            acc_n += nll;
            acc_p += nll * wm;
            mx = fmaxf(mx, wm);
        }
    }

    // reduce 3 waves
#pragma unroll
    for (int off = 32; off > 0; off >>= 1) {
        acc_n += __shfl_down(acc_n, off);
        acc_p += __shfl_down(acc_p, off);
        mx     = fmaxf(mx, __shfl_down(mx, off));
    }
    __shared__ float s_n[3], s_p[3], s_m[3];
    int wid  = tid >> 6;
    int lane = tid & 63;
    if (lane == 0) { s_n[wid] = acc_n; s_p[wid] = acc_p; s_m[wid] = mx; }
    __syncthreads();
    if (tid == 0) {
        p_nll[blockIdx.x] = s_n[0] + s_n[1] + s_n[2];
        p_nw[blockIdx.x]  = s_p[0] + s_p[1] + s_p[2];
        p_wm[blockIdx.x]  = fmaxf(s_m[0], fmaxf(s_m[1], s_m[2]));
    }
}

// ---------------------------------------------------------------------------
// k_fin: reduce LBLKS partials -> scalar loss (single block)
// ---------------------------------------------------------------------------
__global__ __launch_bounds__(256) void k_fin(const float* __restrict__ pn,
                                             const float* __restrict__ pw,
                                             const float* __restrict__ pm,
                                             float* __restrict__ out) {
    double s = 0.0, p = 0.0;
    float mx = 0.f;
    for (int t = threadIdx.x; t < LBLKS; t += 256) {
        s += (double)pn[t];
        p += (double)pw[t];
        mx = fmaxf(mx, pm[t]);
    }
#pragma unroll
    for (int off = 32; off > 0; off >>= 1) {
        s  += __shfl_down(s, off);
        p  += __shfl_down(p, off);
        mx  = fmaxf(mx, __shfl_down(mx, off));
    }
    __shared__ double sh_s[4], sh_p[4];
    __shared__ float  sh_m[4];
    int wid  = threadIdx.x >> 6;
    int lane = threadIdx.x & 63;
    if (lane == 0) { sh_s[wid] = s; sh_p[wid] = p; sh_m[wid] = mx; }
    __syncthreads();
    if (threadIdx.x == 0) {
        double S = 0.0, P = 0.0;
        float  M = 0.f;
#pragma unroll
        for (int t = 0; t < 4; ++t) { S += sh_s[t]; P += sh_p[t]; M = fmaxf(M, sh_m[t]); }
        double res = (M > 0.f) ? (S + 2.0 * P / (double)M) : S;
        out[0] = (float)(res / (double)NV);
    }
}

extern "C" void kernel_launch(void* const* d_in, const int* in_sizes, int n_in,
                              void* d_out, int out_size, void* d_ws, size_t ws_size,
                              hipStream_t stream) {
    const float* logits = (const float*)d_in[0];
    const int*   labels = (const int*)d_in[1];
    float*       out    = (float*)d_out;

    char* ws = (char*)d_ws;
    float* p_nll = (float*)ws;                          // LBLKS floats
    float* p_nw  = (float*)(ws + 16384);                // LBLKS floats
    float* p_wm  = (float*)(ws + 32768);                // LBLKS floats
    unsigned short* ys = (unsigned short*)(ws + 65536);
    // ws use: 64 KB + NV*2 B ~= 14.2 MB; all written every call -> no memset.

    k_wh  <<<WHBLKS, 256, 0, stream>>>(labels, ys);
    k_loss<<<LBLKS, 192, 0, stream>>>(ys, logits, p_nll, p_nw, p_wm);
    k_fin <<<1, 256, 0, stream>>>(p_nll, p_nw, p_wm, out);
}

// Round 7
// 45.008 us; speedup vs baseline: 2.6049x; 1.0106x over previous
//
#include <hip/hip_runtime.h>

// Problem dims (fixed by reference)
#define BB 2
#define CC 2
#define DD 96
#define HH 192
#define WW 192
static constexpr int NV   = BB * DD * HH * WW;   // 7,077,888 voxels
static constexpr int HW_  = HH * WW;             // 36,864
static constexpr int DHW_ = DD * HW_;            // 3,538,944
static constexpr int QPR  = WW / 4;              // 48 int4-quads per row

// k_wh geometry: block = (b,d) slice x 8-quad W-segment, full H in LDS
static constexpr int SEGQ = 8;                   // quads per segment (32 voxels)
static constexpr int NSEG = QPR / SEGQ;          // 6
static constexpr int LSTR = SEGQ + 1;            // LDS row stride (uint2), padded
static constexpr int WHBLKS = BB * DD * NSEG;    // 1152

// k_loss geometry: rolling-D. Thread = (b,h,w4) column x DCH-deep d-chunk.
static constexpr int W4   = 48;                  // 4-voxel groups per row
static constexpr int COLS = BB * HH * W4;        // 18,432 columns
static constexpr int DCH  = 8;                   // d outputs per thread
static constexpr int NCH  = DD / DCH;            // 12 chunks
static constexpr int CBLK = COLS / 256;          // 72 column-blocks
static constexpr int LBLKS = CBLK * NCH;         // 864 blocks

// fixed-point window-combination constants: 27*125*343 = 1,157,625
// fq = (cnum - 2*(S3*42875 + S5*9261 + S7*3375)) / 1157625   (exact in int)
#define K3 42875
#define K5 9261
#define K7 3375

// packed-field masks (2 ushorts per uint32)
#define PM1  0x00010001u
#define PM3  0x00030003u
#define PM7  0x00070007u
#define PMF  0x000F000Fu
#define PM1F 0x001F001Fu
#define PM3F 0x003F3F3Fu  // placeholder guard; real mask defined below
#undef  PM3F
#define PM3F 0x003F003Fu

// ---------------------------------------------------------------------------
// k_wh: fused W-window + H-window sums (R4-verified, unchanged).
// ---------------------------------------------------------------------------
__device__ __forceinline__ unsigned ypack(const unsigned* g) {
    unsigned t3 = ((g[2] >> 1) & PM3) + ((g[3] >> 1) & PM3) + ((g[4] >> 1) & PM3);
    unsigned t5 = ((g[1] >> 3) & PM7) + ((g[2] >> 3) & PM7) + ((g[3] >> 3) & PM7)
                + ((g[4] >> 3) & PM7) + ((g[5] >> 3) & PM7);
    unsigned t7 = ((g[0] >> 6) & PM7) + ((g[1] >> 6) & PM7) + ((g[2] >> 6) & PM7)
                + ((g[3] >> 6) & PM7) + ((g[4] >> 6) & PM7) + ((g[5] >> 6) & PM7)
                + ((g[6] >> 6) & PM7);
    return (g[3] & PM1) | (t3 << 1) | (t5 << 5) | (t7 << 10);
}

__global__ __launch_bounds__(256) void k_wh(const int* __restrict__ lab,
                                            unsigned short* __restrict__ ys) {
    __shared__ uint2 lds[HH * LSTR];             // 13,824 B
    int blk  = blockIdx.x;
    int seg  = blk % NSEG;
    int bd   = blk / NSEG;                       // (b*DD + d), 0..191
    int base = bd * HW_;                         // voxel index of (b,d,0,0)
    const int4* l4 = (const int4*)lab;
    int bq = base >> 2;

    // ---- Stage A: W-sums -> LDS -----------------------------------------
    for (int t = threadIdx.x; t < HH * SEGQ; t += 256) {
        int row  = t >> 3;
        int qloc = t & 7;
        int gq   = seg * SEGQ + qloc;
        int qi   = bq + row * QPR + gq;
        int4 cur = l4[qi];
        int4 prv = (gq > 0)       ? l4[qi - 1] : int4{0, 0, 0, 0};
        int4 nxt = (gq < QPR - 1) ? l4[qi + 1] : int4{0, 0, 0, 0};
        int v[12] = {prv.x, prv.y, prv.z, prv.w,
                     cur.x, cur.y, cur.z, cur.w,
                     nxt.x, nxt.y, nxt.z, nxt.w};
        int s7[4], s5[4], s3[4];
        s7[0] = v[1] + v[2] + v[3] + v[4] + v[5] + v[6] + v[7];
#pragma unroll
        for (int j = 0; j < 3; ++j) s7[j + 1] = s7[j] - v[j + 1] + v[j + 8];
#pragma unroll
        for (int j = 0; j < 4; ++j) {
            s5[j] = s7[j] - v[j + 1] - v[j + 7];
            s3[j] = s5[j] - v[j + 2] - v[j + 6];
        }
        unsigned o0 = (unsigned)(v[4] | (s3[0] << 1) | (s5[0] << 3) | (s7[0] << 6));
        unsigned o1 = (unsigned)(v[5] | (s3[1] << 1) | (s5[1] << 3) | (s7[1] << 6));
        unsigned o2 = (unsigned)(v[6] | (s3[2] << 1) | (s5[2] << 3) | (s7[2] << 6));
        unsigned o3 = (unsigned)(v[7] | (s3[3] << 1) | (s5[3] << 3) | (s7[3] << 6));
        uint2 st;
        st.x = o0 | (o1 << 16);
        st.y = o2 | (o3 << 16);
        lds[row * LSTR + qloc] = st;
    }
    __syncthreads();

    // ---- Stage B: H-sums -> ys ------------------------------------------
    for (int t = threadIdx.x; t < HH * SEGQ; t += 256) {
        int row  = t >> 3;
        int qloc = t & 7;
        int gq   = seg * SEGQ + qloc;
        unsigned gx[7], gy[7];
#pragma unroll
        for (int k = 0; k < 7; ++k) {
            int hh = row + k - 3;
            if (hh >= 0 && hh < HH) {
                uint2 u = lds[hh * LSTR + qloc];
                gx[k] = u.x; gy[k] = u.y;
            } else { gx[k] = 0u; gy[k] = 0u; }
        }
        uint2 st;
        st.x = ypack(gx);
        st.y = ypack(gy);
        *(uint2*)(ys + base + row * WW + gq * 4) = st;
    }
}

// ---------------------------------------------------------------------------
// k_loss: rolling-D register window. Each thread owns a (b,h,w4) column and
// walks DCH d-outputs; each ys slice is loaded ONCE (uint2), fields extracted
// once into rings e3[5]/e5[6]/e7[7]/raw[4] (statically indexed under full
// unroll). S3/S5/S7 = 12 packed adds per step. No atomics, no fences.
// ---------------------------------------------------------------------------
__global__ __launch_bounds__(256) void k_loss(const unsigned short* __restrict__ ys,
                                              const float* __restrict__ logits,
                                              float* __restrict__ p_nll,
                                              float* __restrict__ p_nw,
                                              float* __restrict__ p_wm) {
    int tid   = threadIdx.x;
    int cb    = blockIdx.x % CBLK;
    int chunk = blockIdx.x / CBLK;               // block-uniform d-chunk
    int col   = cb * 256 + tid;
    int w4    = col % W4;
    int rowid = col / W4;                        // b*HH + h
    int h     = rowid % HH;
    int b     = rowid / HH;
    int d0    = chunk * DCH;
    int w0    = w4 * 4;

    int i_bh = b * DHW_ + h * WW + w0;           // voxel idx at d=0
    const float* lp = logits + i_bh + b * DHW_ + d0 * HW_;  // c=0 at dout=d0

    int ch3 = 1 + min(h, 1) + min(HH - 1 - h, 1);
    int ch5 = 1 + min(h, 2) + min(HH - 1 - h, 2);
    int ch7 = 1 + min(h, 3) + min(HH - 1 - h, 3);
    bool interior = (w4 > 0) && (w4 < W4 - 1);

    unsigned e3[5][2], e5[6][2], e7[7][2], ur[4][2];
    float acc_n = 0.f, acc_p = 0.f, mx = 0.f;

#pragma unroll
    for (int step = 0; step < DCH + 6; ++step) {
        int ld = d0 - 3 + step;                  // slice being loaded
        uint2 t2 = {0u, 0u};
        if (ld >= 0 && ld < DD)                  // block-uniform branch
            t2 = *(const uint2*)(ys + i_bh + ld * HW_);
        {
            unsigned u0 = t2.x, u1 = t2.y;
            ur[step % 4][0] = u0;                 ur[step % 4][1] = u1;
            e3[step % 5][0] = (u0 >> 1) & PMF;    e3[step % 5][1] = (u1 >> 1) & PMF;
            e5[step % 6][0] = (u0 >> 5) & PM1F;   e5[step % 6][1] = (u1 >> 5) & PM1F;
            e7[step % 7][0] = (u0 >> 10) & PM3F;  e7[step % 7][1] = (u1 >> 10) & PM3F;
        }
        if (step >= 6) {
            int dout = ld - 3;                   // = d0 + step - 6
            unsigned S3w[2], S5w[2], S7w[2], lw[2];
#pragma unroll
            for (int wd = 0; wd < 2; ++wd) {
                S3w[wd] = e3[(step - 4) % 5][wd] + e3[(step - 3) % 5][wd]
                        + e3[(step - 2) % 5][wd];
                S5w[wd] = e5[(step - 5) % 6][wd] + e5[(step - 4) % 6][wd]
                        + e5[(step - 3) % 6][wd] + e5[(step - 2) % 6][wd]
                        + e5[(step - 1) % 6][wd];
                S7w[wd] = e7[(step - 6) % 7][wd] + e7[(step - 5) % 7][wd]
                        + e7[(step - 4) % 7][wd] + e7[(step - 3) % 7][wd]
                        + e7[(step - 2) % 7][wd] + e7[(step - 1) % 7][wd]
                        + e7[(step - 0) % 7][wd];
                lw[wd]  = ur[(step - 3) % 4][wd];
            }
            int cd3 = 1 + min(dout, 1) + min(DD - 1 - dout, 1);
            int cd5 = 1 + min(dout, 2) + min(DD - 1 - dout, 2);
            int cd7 = 1 + min(dout, 3) + min(DD - 1 - dout, 3);
            int A3 = ch3 * cd3 * K3;             // <= 385,875 < 2^24
            int B5 = ch5 * cd5 * K5;             // <= 231,525 < 2^24
            int C7 = ch7 * cd7 * K7;             // <= 165,375 < 2^24
            int inum = 3 * A3 + 5 * B5 + 7 * C7;

            const float4 L0 = *(const float4*)(lp + (step - 6) * HW_);
            const float4 L1 = *(const float4*)(lp + (step - 6) * HW_ + DHW_);
            float l0[4] = {L0.x, L0.y, L0.z, L0.w};
            float l1[4] = {L1.x, L1.y, L1.z, L1.w};

#pragma unroll
            for (int j = 0; j < 4; ++j) {
                const int wd = j >> 1;
                const int sh = (j & 1) * 16;
                int S3j  = (int)((S3w[wd] >> sh) & 0xFFFFu);
                int S5j  = (int)((S5w[wd] >> sh) & 0xFFFFu);
                int S7j  = (int)((S7w[wd] >> sh) & 0xFFFFu);
                int labj = (int)((lw[wd] >> sh) & 1u);

                int Ssum = __mul24(S3j, K3) + __mul24(S5j, K5) + __mul24(S7j, K7);
                int cn = inum;
                if (!interior) {
                    int w = w0 + j;
                    int cw3 = 1 + min(w, 1) + min(WW - 1 - w, 1);
                    int cw5 = 1 + min(w, 2) + min(WW - 1 - w, 2);
                    int cw7 = 1 + min(w, 3) + min(WW - 1 - w, 3);
                    cn = __mul24(cw3, A3) + __mul24(cw5, B5) + __mul24(cw7, C7);
                }
                float fq  = (float)(cn - 2 * Ssum) * (1.0f / 1157625.0f);
                float sgn = labj ? 1.0f : -1.0f;
                float wm  = fmaf(sgn, fq, 3.0f);
                float s   = sgn * (l0[j] - l1[j]);
                float nll = fmaxf(s, 0.f) + __logf(1.0f + __expf(-fabsf(s)));

                acc_n += nll;
                acc_p += nll * wm;
                mx = fmaxf(mx, wm);
            }
        }
    }

    // reduce 4 waves
#pragma unroll
    for (int off = 32; off > 0; off >>= 1) {
        acc_n += __shfl_down(acc_n, off);
        acc_p += __shfl_down(acc_p, off);
        mx     = fmaxf(mx, __shfl_down(mx, off));
    }
    __shared__ float s_n[4], s_p[4], s_m[4];
    int wid  = tid >> 6;
    int lane = tid & 63;
    if (lane == 0) { s_n[wid] = acc_n; s_p[wid] = acc_p; s_m[wid] = mx; }
    __syncthreads();
    if (tid == 0) {
        p_nll[blockIdx.x] = s_n[0] + s_n[1] + s_n[2] + s_n[3];
        p_nw[blockIdx.x]  = s_p[0] + s_p[1] + s_p[2] + s_p[3];
        p_wm[blockIdx.x]  = fmaxf(fmaxf(s_m[0], s_m[1]), fmaxf(s_m[2], s_m[3]));
    }
}

// ---------------------------------------------------------------------------
// k_fin: reduce LBLKS partials -> scalar loss (single block)
// ---------------------------------------------------------------------------
__global__ __launch_bounds__(256) void k_fin(const float* __restrict__ pn,
                                             const float* __restrict__ pw,
                                             const float* __restrict__ pm,
                                             float* __restrict__ out) {
    double s = 0.0, p = 0.0;
    float mx = 0.f;
    for (int t = threadIdx.x; t < LBLKS; t += 256) {
        s += (double)pn[t];
        p += (double)pw[t];
        mx = fmaxf(mx, pm[t]);
    }
#pragma unroll
    for (int off = 32; off > 0; off >>= 1) {
        s  += __shfl_down(s, off);
        p  += __shfl_down(p, off);
        mx  = fmaxf(mx, __shfl_down(mx, off));
    }
    __shared__ double sh_s[4], sh_p[4];
    __shared__ float  sh_m[4];
    int wid  = threadIdx.x >> 6;
    int lane = threadIdx.x & 63;
    if (lane == 0) { sh_s[wid] = s; sh_p[wid] = p; sh_m[wid] = mx; }
    __syncthreads();
    if (threadIdx.x == 0) {
        double S = 0.0, P = 0.0;
        float  M = 0.f;
#pragma unroll
        for (int t = 0; t < 4; ++t) { S += sh_s[t]; P += sh_p[t]; M = fmaxf(M, sh_m[t]); }
        double res = (M > 0.f) ? (S + 2.0 * P / (double)M) : S;
        out[0] = (float)(res / (double)NV);
    }
}

extern "C" void kernel_launch(void* const* d_in, const int* in_sizes, int n_in,
                              void* d_out, int out_size, void* d_ws, size_t ws_size,
                              hipStream_t stream) {
    const float* logits = (const float*)d_in[0];
    const int*   labels = (const int*)d_in[1];
    float*       out    = (float*)d_out;

    char* ws = (char*)d_ws;
    float* p_nll = (float*)ws;                          // LBLKS floats
    float* p_nw  = (float*)(ws + 16384);                // LBLKS floats
    float* p_wm  = (float*)(ws + 32768);                // LBLKS floats
    unsigned short* ys = (unsigned short*)(ws + 65536);
    // ws use: 64 KB + NV*2 B ~= 14.2 MB; all written every call -> no memset.

    k_wh  <<<WHBLKS, 256, 0, stream>>>(labels, ys);
    k_loss<<<LBLKS, 256, 0, stream>>>(ys, logits, p_nll, p_nw, p_wm);
    k_fin <<<1, 256, 0, stream>>>(p_nll, p_nw, p_wm, out);
}

// Round 8
// 42.041 us; speedup vs baseline: 2.7888x; 1.0706x over previous
//
#include <hip/hip_runtime.h>

// Problem dims (fixed by reference)
#define BB 2
#define CC 2
#define DD 96
#define HH 192
#define WW 192
static constexpr int NV   = BB * DD * HH * WW;   // 7,077,888 voxels
static constexpr int HW_  = HH * WW;             // 36,864
static constexpr int DHW_ = DD * HW_;            // 3,538,944
static constexpr int QPR  = WW / 4;              // 48 int4-quads per row

// k_wh geometry: block = (b,d) slice x 8-quad W-segment, full H in LDS
static constexpr int SEGQ = 8;                   // quads per segment (32 voxels)
static constexpr int NSEG = QPR / SEGQ;          // 6
static constexpr int LSTR = SEGQ + 1;            // LDS row stride (uint2), padded
static constexpr int WHBLKS = BB * DD * NSEG;    // 1152

// k_loss geometry: rolling-D. Thread = (b,h,w4) column x DCH-deep d-chunk.
// DCH=4 (not 8): 1728 blocks x 4 waves = 6912 waves — restores R6's wave
// count; R7's DCH=8 gave only 3456 waves -> 26% occupancy, latency-bound.
static constexpr int W4   = 48;                  // 4-voxel groups per row
static constexpr int COLS = BB * HH * W4;        // 18,432 columns
static constexpr int DCH  = 4;                   // d outputs per thread
static constexpr int NCH  = DD / DCH;            // 24 chunks
static constexpr int CBLK = COLS / 256;          // 72 column-blocks
static constexpr int LBLKS = CBLK * NCH;         // 1728 blocks

// fixed-point window-combination constants: 27*125*343 = 1,157,625
// fq = (cnum - 2*(S3*42875 + S5*9261 + S7*3375)) / 1157625   (exact in int)
#define K3 42875
#define K5 9261
#define K7 3375

// packed-field masks (2 ushorts per uint32)
#define PM1  0x00010001u
#define PM3  0x00030003u
#define PM7  0x00070007u
#define PMF  0x000F000Fu
#define PM1F 0x001F001Fu
#define PM3F 0x003F003Fu

// ---------------------------------------------------------------------------
// k_wh: fused W-window + H-window sums (R4-verified, unchanged).
// ---------------------------------------------------------------------------
__device__ __forceinline__ unsigned ypack(const unsigned* g) {
    unsigned t3 = ((g[2] >> 1) & PM3) + ((g[3] >> 1) & PM3) + ((g[4] >> 1) & PM3);
    unsigned t5 = ((g[1] >> 3) & PM7) + ((g[2] >> 3) & PM7) + ((g[3] >> 3) & PM7)
                + ((g[4] >> 3) & PM7) + ((g[5] >> 3) & PM7);
    unsigned t7 = ((g[0] >> 6) & PM7) + ((g[1] >> 6) & PM7) + ((g[2] >> 6) & PM7)
                + ((g[3] >> 6) & PM7) + ((g[4] >> 6) & PM7) + ((g[5] >> 6) & PM7)
                + ((g[6] >> 6) & PM7);
    return (g[3] & PM1) | (t3 << 1) | (t5 << 5) | (t7 << 10);
}

__global__ __launch_bounds__(256) void k_wh(const int* __restrict__ lab,
                                            unsigned short* __restrict__ ys) {
    __shared__ uint2 lds[HH * LSTR];             // 13,824 B
    int blk  = blockIdx.x;
    int seg  = blk % NSEG;
    int bd   = blk / NSEG;                       // (b*DD + d), 0..191
    int base = bd * HW_;                         // voxel index of (b,d,0,0)
    const int4* l4 = (const int4*)lab;
    int bq = base >> 2;

    // ---- Stage A: W-sums -> LDS -----------------------------------------
    for (int t = threadIdx.x; t < HH * SEGQ; t += 256) {
        int row  = t >> 3;
        int qloc = t & 7;
        int gq   = seg * SEGQ + qloc;
        int qi   = bq + row * QPR + gq;
        int4 cur = l4[qi];
        int4 prv = (gq > 0)       ? l4[qi - 1] : int4{0, 0, 0, 0};
        int4 nxt = (gq < QPR - 1) ? l4[qi + 1] : int4{0, 0, 0, 0};
        int v[12] = {prv.x, prv.y, prv.z, prv.w,
                     cur.x, cur.y, cur.z, cur.w,
                     nxt.x, nxt.y, nxt.z, nxt.w};
        int s7[4], s5[4], s3[4];
        s7[0] = v[1] + v[2] + v[3] + v[4] + v[5] + v[6] + v[7];
#pragma unroll
        for (int j = 0; j < 3; ++j) s7[j + 1] = s7[j] - v[j + 1] + v[j + 8];
#pragma unroll
        for (int j = 0; j < 4; ++j) {
            s5[j] = s7[j] - v[j + 1] - v[j + 7];
            s3[j] = s5[j] - v[j + 2] - v[j + 6];
        }
        unsigned o0 = (unsigned)(v[4] | (s3[0] << 1) | (s5[0] << 3) | (s7[0] << 6));
        unsigned o1 = (unsigned)(v[5] | (s3[1] << 1) | (s5[1] << 3) | (s7[1] << 6));
        unsigned o2 = (unsigned)(v[6] | (s3[2] << 1) | (s5[2] << 3) | (s7[2] << 6));
        unsigned o3 = (unsigned)(v[7] | (s3[3] << 1) | (s5[3] << 3) | (s7[3] << 6));
        uint2 st;
        st.x = o0 | (o1 << 16);
        st.y = o2 | (o3 << 16);
        lds[row * LSTR + qloc] = st;
    }
    __syncthreads();

    // ---- Stage B: H-sums -> ys ------------------------------------------
    for (int t = threadIdx.x; t < HH * SEGQ; t += 256) {
        int row  = t >> 3;
        int qloc = t & 7;
        int gq   = seg * SEGQ + qloc;
        unsigned gx[7], gy[7];
#pragma unroll
        for (int k = 0; k < 7; ++k) {
            int hh = row + k - 3;
            if (hh >= 0 && hh < HH) {
                uint2 u = lds[hh * LSTR + qloc];
                gx[k] = u.x; gy[k] = u.y;
            } else { gx[k] = 0u; gy[k] = 0u; }
        }
        uint2 st;
        st.x = ypack(gx);
        st.y = ypack(gy);
        *(uint2*)(ys + base + row * WW + gq * 4) = st;
    }
}

// ---------------------------------------------------------------------------
// k_loss: rolling-D register window, DCH=4. Each thread owns a (b,h,w4)
// column; each ys slice loaded ONCE (uint2), fields extracted once into
// rings e3[5]/e5[6]/e7[7]/ur[4] (statically indexed under full unroll).
// ---------------------------------------------------------------------------
__global__ __launch_bounds__(256) void k_loss(const unsigned short* __restrict__ ys,
                                              const float* __restrict__ logits,
                                              float* __restrict__ p_nll,
                                              float* __restrict__ p_nw,
                                              float* __restrict__ p_wm) {
    int tid   = threadIdx.x;
    int cb    = blockIdx.x % CBLK;
    int chunk = blockIdx.x / CBLK;               // block-uniform d-chunk
    int col   = cb * 256 + tid;
    int w4    = col % W4;
    int rowid = col / W4;                        // b*HH + h
    int h     = rowid % HH;
    int b     = rowid / HH;
    int d0    = chunk * DCH;
    int w0    = w4 * 4;

    int i_bh = b * DHW_ + h * WW + w0;           // voxel idx at d=0
    const float* lp = logits + i_bh + b * DHW_ + d0 * HW_;  // c=0 at dout=d0

    int ch3 = 1 + min(h, 1) + min(HH - 1 - h, 1);
    int ch5 = 1 + min(h, 2) + min(HH - 1 - h, 2);
    int ch7 = 1 + min(h, 3) + min(HH - 1 - h, 3);
    bool interior = (w4 > 0) && (w4 < W4 - 1);

    unsigned e3[5][2], e5[6][2], e7[7][2], ur[4][2];
    float acc_n = 0.f, acc_p = 0.f, mx = 0.f;

#pragma unroll
    for (int step = 0; step < DCH + 6; ++step) {
        int ld = d0 - 3 + step;                  // slice being loaded
        uint2 t2 = {0u, 0u};
        if (ld >= 0 && ld < DD)                  // block-uniform branch
            t2 = *(const uint2*)(ys + i_bh + ld * HW_);
        {
            unsigned u0 = t2.x, u1 = t2.y;
            ur[step % 4][0] = u0;                 ur[step % 4][1] = u1;
            e3[step % 5][0] = (u0 >> 1) & PMF;    e3[step % 5][1] = (u1 >> 1) & PMF;
            e5[step % 6][0] = (u0 >> 5) & PM1F;   e5[step % 6][1] = (u1 >> 5) & PM1F;
            e7[step % 7][0] = (u0 >> 10) & PM3F;  e7[step % 7][1] = (u1 >> 10) & PM3F;
        }
        if (step >= 6) {
            int dout = ld - 3;                   // = d0 + step - 6
            unsigned S3w[2], S5w[2], S7w[2], lw[2];
#pragma unroll
            for (int wd = 0; wd < 2; ++wd) {
                S3w[wd] = e3[(step - 4) % 5][wd] + e3[(step - 3) % 5][wd]
                        + e3[(step - 2) % 5][wd];
                S5w[wd] = e5[(step - 5) % 6][wd] + e5[(step - 4) % 6][wd]
                        + e5[(step - 3) % 6][wd] + e5[(step - 2) % 6][wd]
                        + e5[(step - 1) % 6][wd];
                S7w[wd] = e7[(step - 6) % 7][wd] + e7[(step - 5) % 7][wd]
                        + e7[(step - 4) % 7][wd] + e7[(step - 3) % 7][wd]
                        + e7[(step - 2) % 7][wd] + e7[(step - 1) % 7][wd]
                        + e7[(step - 0) % 7][wd];
                lw[wd]  = ur[(step - 3) % 4][wd];
            }
            int cd3 = 1 + min(dout, 1) + min(DD - 1 - dout, 1);
            int cd5 = 1 + min(dout, 2) + min(DD - 1 - dout, 2);
            int cd7 = 1 + min(dout, 3) + min(DD - 1 - dout, 3);
            int A3 = ch3 * cd3 * K3;             // <= 385,875 < 2^24
            int B5 = ch5 * cd5 * K5;             // <= 231,525 < 2^24
            int C7 = ch7 * cd7 * K7;             // <= 165,375 < 2^24
            int inum = 3 * A3 + 5 * B5 + 7 * C7;

            const float4 L0 = *(const float4*)(lp + (step - 6) * HW_);
            const float4 L1 = *(const float4*)(lp + (step - 6) * HW_ + DHW_);
            float l0[4] = {L0.x, L0.y, L0.z, L0.w};
            float l1[4] = {L1.x, L1.y, L1.z, L1.w};

#pragma unroll
            for (int j = 0; j < 4; ++j) {
                const int wd = j >> 1;
                const int sh = (j & 1) * 16;
                int S3j  = (int)((S3w[wd] >> sh) & 0xFFFFu);
                int S5j  = (int)((S5w[wd] >> sh) & 0xFFFFu);
                int S7j  = (int)((S7w[wd] >> sh) & 0xFFFFu);
                int labj = (int)((lw[wd] >> sh) & 1u);

                int Ssum = __mul24(S3j, K3) + __mul24(S5j, K5) + __mul24(S7j, K7);
                int cn = inum;
                if (!interior) {
                    int w = w0 + j;
                    int cw3 = 1 + min(w, 1) + min(WW - 1 - w, 1);
                    int cw5 = 1 + min(w, 2) + min(WW - 1 - w, 2);
                    int cw7 = 1 + min(w, 3) + min(WW - 1 - w, 3);
                    cn = __mul24(cw3, A3) + __mul24(cw5, B5) + __mul24(cw7, C7);
                }
                float fq  = (float)(cn - 2 * Ssum) * (1.0f / 1157625.0f);
                float sgn = labj ? 1.0f : -1.0f;
                float wm  = fmaf(sgn, fq, 3.0f);
                float s   = sgn * (l0[j] - l1[j]);
                float nll = fmaxf(s, 0.f) + __logf(1.0f + __expf(-fabsf(s)));

                acc_n += nll;
                acc_p += nll * wm;
                mx = fmaxf(mx, wm);
            }
        }
    }

    // reduce 4 waves
#pragma unroll
    for (int off = 32; off > 0; off >>= 1) {
        acc_n += __shfl_down(acc_n, off);
        acc_p += __shfl_down(acc_p, off);
        mx     = fmaxf(mx, __shfl_down(mx, off));
    }
    __shared__ float s_n[4], s_p[4], s_m[4];
    int wid  = tid >> 6;
    int lane = tid & 63;
    if (lane == 0) { s_n[wid] = acc_n; s_p[wid] = acc_p; s_m[wid] = mx; }
    __syncthreads();
    if (tid == 0) {
        p_nll[blockIdx.x] = s_n[0] + s_n[1] + s_n[2] + s_n[3];
        p_nw[blockIdx.x]  = s_p[0] + s_p[1] + s_p[2] + s_p[3];
        p_wm[blockIdx.x]  = fmaxf(fmaxf(s_m[0], s_m[1]), fmaxf(s_m[2], s_m[3]));
    }
}

// ---------------------------------------------------------------------------
// k_fin: reduce LBLKS partials -> scalar loss (single block)
// ---------------------------------------------------------------------------
__global__ __launch_bounds__(256) void k_fin(const float* __restrict__ pn,
                                             const float* __restrict__ pw,
                                             const float* __restrict__ pm,
                                             float* __restrict__ out) {
    double s = 0.0, p = 0.0;
    float mx = 0.f;
    for (int t = threadIdx.x; t < LBLKS; t += 256) {
        s += (double)pn[t];
        p += (double)pw[t];
        mx = fmaxf(mx, pm[t]);
    }
#pragma unroll
    for (int off = 32; off > 0; off >>= 1) {
        s  += __shfl_down(s, off);
        p  += __shfl_down(p, off);
        mx  = fmaxf(mx, __shfl_down(mx, off));
    }
    __shared__ double sh_s[4], sh_p[4];
    __shared__ float  sh_m[4];
    int wid  = threadIdx.x >> 6;
    int lane = threadIdx.x & 63;
    if (lane == 0) { sh_s[wid] = s; sh_p[wid] = p; sh_m[wid] = mx; }
    __syncthreads();
    if (threadIdx.x == 0) {
        double S = 0.0, P = 0.0;
        float  M = 0.f;
#pragma unroll
        for (int t = 0; t < 4; ++t) { S += sh_s[t]; P += sh_p[t]; M = fmaxf(M, sh_m[t]); }
        double res = (M > 0.f) ? (S + 2.0 * P / (double)M) : S;
        out[0] = (float)(res / (double)NV);
    }
}

extern "C" void kernel_launch(void* const* d_in, const int* in_sizes, int n_in,
                              void* d_out, int out_size, void* d_ws, size_t ws_size,
                              hipStream_t stream) {
    const float* logits = (const float*)d_in[0];
    const int*   labels = (const int*)d_in[1];
    float*       out    = (float*)d_out;

    char* ws = (char*)d_ws;
    float* p_nll = (float*)ws;                          // LBLKS floats
    float* p_nw  = (float*)(ws + 16384);                // LBLKS floats
    float* p_wm  = (float*)(ws + 32768);                // LBLKS floats
    unsigned short* ys = (unsigned short*)(ws + 65536);
    // ws use: 64 KB + NV*2 B ~= 14.2 MB; all written every call -> no memset.

    k_wh  <<<WHBLKS, 256, 0, stream>>>(labels, ys);
    k_loss<<<LBLKS, 256, 0, stream>>>(ys, logits, p_nll, p_nw, p_wm);
    k_fin <<<1, 256, 0, stream>>>(p_nll, p_nw, p_wm, out);
}